// Round 2
// baseline (545.136 us; speedup 1.0000x reference)
//
#include <hip/hip_runtime.h>
#include <hip/hip_bf16.h>

#define BB 4
#define NN 2048
#define DD 256
#define HH 8
#define HDD 32
#define MASK_WORDS (NN / 32)   // 64 u32 per row

typedef __hip_bfloat16 bf16;

__device__ __forceinline__ float u16_to_bf16f(unsigned short w) {
    unsigned u = ((unsigned)w) << 16;
    return __uint_as_float(u);
}

// detect whether float tensors are stored as bf16 (vs f32) from the
// temperature scalar: bf16 -> first u16 is ~5.66; f32 -> first u16 is
// mantissa low bits (~1e-35 as bf16). Deterministic, wave-uniform.
__device__ __forceinline__ int detect_bf16(const unsigned short* tptr) {
    float t0 = u16_to_bf16f(tptr[0]);
    return (t0 > 1.0f && t0 < 16.0f) ? 1 : 0;
}

__device__ __forceinline__ float get_temp(const unsigned short* tptr, int isbf) {
    if (isbf) return u16_to_bf16f(tptr[0]);
    return ((const float*)tptr)[0];
}

__device__ __forceinline__ float ldf(const void* p, size_t i, int isbf) {
    if (isbf) return __bfloat162float(((const bf16*)p)[i]);
    return ((const float*)p)[i];
}

__device__ __forceinline__ void stf(void* p, size_t i, float v, int isbf) {
    if (isbf) ((bf16*)p)[i] = __float2bfloat16(v);
    else      ((float*)p)[i] = v;
}

// ---------------- mask build (handles int32 or int64 edge_index) ----------------
__global__ void build_mask_kernel(const unsigned* __restrict__ ei_raw, int E,
                                  unsigned* __restrict__ mask) {
    // int64 little-endian: odd u32 words of first 8 indices are all zero.
    bool is64 = true;
    for (int i = 1; i < 16; i += 2) {
        if (ei_raw[i] != 0u) { is64 = false; break; }
    }
    int e = blockIdx.x * blockDim.x + threadIdx.x;
    if (e < E) {
        int s, d;
        if (is64) {
            s = (int)ei_raw[(size_t)2 * e];
            d = (int)ei_raw[(size_t)2 * (E + e)];
        } else {
            s = ((const int*)ei_raw)[e];
            d = ((const int*)ei_raw)[E + e];
        }
        atomicOr(&mask[(size_t)s * MASK_WORDS + (d >> 5)], 1u << (d & 31));
        atomicOr(&mask[(size_t)d * MASK_WORDS + (s >> 5)], 1u << (s & 31));
    }
    if (e < NN) {
        atomicOr(&mask[(size_t)e * MASK_WORDS + (e >> 5)], 1u << (e & 31));
    }
}

// ---------------- QKV projection: X[8192,256] @ W[256,256]^T + b -> fp32 [B,H,N,HD] ----------------
__global__ __launch_bounds__(256) void proj_qkv_kernel(
        const void* __restrict__ X, const void* __restrict__ W,
        const void* __restrict__ bias, const unsigned short* __restrict__ tptr,
        float* __restrict__ out) {
    __shared__ float Xs[32][17];
    __shared__ float Ws[32][17];
    int isbf = detect_bf16(tptr);
    int tid = threadIdx.x;
    int tx = tid & 15, ty = tid >> 4;
    int row0 = blockIdx.y * 32, col0 = blockIdx.x * 32;
    float acc[2][2] = {{0.f, 0.f}, {0.f, 0.f}};
    for (int kt = 0; kt < DD; kt += 16) {
        for (int i = tid; i < 32 * 16; i += 256) {
            int r = i >> 4, k = i & 15;
            Xs[r][k] = ldf(X, (size_t)(row0 + r) * DD + kt + k, isbf);
            Ws[r][k] = ldf(W, (size_t)(col0 + r) * DD + kt + k, isbf);
        }
        __syncthreads();
#pragma unroll
        for (int k = 0; k < 16; k++) {
            float a0 = Xs[2 * ty][k], a1 = Xs[2 * ty + 1][k];
            float b0 = Ws[2 * tx][k], b1 = Ws[2 * tx + 1][k];
            acc[0][0] += a0 * b0; acc[0][1] += a0 * b1;
            acc[1][0] += a1 * b0; acc[1][1] += a1 * b1;
        }
        __syncthreads();
    }
#pragma unroll
    for (int i = 0; i < 2; i++) {
#pragma unroll
        for (int j = 0; j < 2; j++) {
            int row = row0 + 2 * ty + i;
            int col = col0 + 2 * tx + j;
            float v = acc[i][j] + ldf(bias, col, isbf);
            int b = row >> 11, n = row & (NN - 1);
            int h = col >> 5, d = col & (HDD - 1);
            out[(((size_t)(b * HH + h)) * NN + n) * HDD + d] = v;
        }
    }
}

// ---------------- output projection: att[8192,256](fp32) @ Wo^T + bo -> out dtype ----------------
__global__ __launch_bounds__(256) void out_proj_kernel(
        const float* __restrict__ X, const void* __restrict__ W,
        const void* __restrict__ bias, const unsigned short* __restrict__ tptr,
        void* __restrict__ out) {
    __shared__ float Xs[32][17];
    __shared__ float Ws[32][17];
    int isbf = detect_bf16(tptr);
    int tid = threadIdx.x;
    int tx = tid & 15, ty = tid >> 4;
    int row0 = blockIdx.y * 32, col0 = blockIdx.x * 32;
    float acc[2][2] = {{0.f, 0.f}, {0.f, 0.f}};
    for (int kt = 0; kt < DD; kt += 16) {
        for (int i = tid; i < 32 * 16; i += 256) {
            int r = i >> 4, k = i & 15;
            Xs[r][k] = X[(size_t)(row0 + r) * DD + kt + k];
            Ws[r][k] = ldf(W, (size_t)(col0 + r) * DD + kt + k, isbf);
        }
        __syncthreads();
#pragma unroll
        for (int k = 0; k < 16; k++) {
            float a0 = Xs[2 * ty][k], a1 = Xs[2 * ty + 1][k];
            float b0 = Ws[2 * tx][k], b1 = Ws[2 * tx + 1][k];
            acc[0][0] += a0 * b0; acc[0][1] += a0 * b1;
            acc[1][0] += a1 * b0; acc[1][1] += a1 * b1;
        }
        __syncthreads();
    }
#pragma unroll
    for (int i = 0; i < 2; i++) {
#pragma unroll
        for (int j = 0; j < 2; j++) {
            int row = row0 + 2 * ty + i;
            int col = col0 + 2 * tx + j;
            float v = acc[i][j] + ldf(bias, col, isbf);
            stf(out, (size_t)row * DD + col, v, isbf);
        }
    }
}

// ---------------- sparse masked attention, one block per (b, n) ----------------
__global__ __launch_bounds__(256) void attn_kernel(
        const float* __restrict__ Q, const float* __restrict__ K,
        const float* __restrict__ V, const unsigned* __restrict__ mask,
        const unsigned short* __restrict__ tptr,
        float* __restrict__ att /* [B*N, D] */,
        void* __restrict__ out /* full d_out; attn_mean at element B*N*D */) {
    __shared__ float meanrow[NN];           // 8 KB
    __shared__ float sc[NN];                // 8 KB
    __shared__ unsigned short nbr[NN];      // 4 KB
    __shared__ unsigned mrow[MASK_WORDS];
    __shared__ float q_sh[HDD];
    __shared__ float red[256];
    __shared__ float part_s[8][HDD];
    __shared__ int cnt_s;

    int tid = threadIdx.x;
    int bid = blockIdx.x;
    int b = bid >> 11;
    int n = bid & (NN - 1);

    int isbf = detect_bf16(tptr);
    float inv_temp = 1.0f / get_temp(tptr, isbf);

    for (int i = tid; i < NN; i += 256) meanrow[i] = 0.0f;
    if (tid < MASK_WORDS) mrow[tid] = mask[(size_t)n * MASK_WORDS + tid];
    if (tid == 0) cnt_s = 0;
    __syncthreads();

    for (int m = tid; m < NN; m += 256) {
        if ((mrow[m >> 5] >> (m & 31)) & 1u) {
            int idx = atomicAdd(&cnt_s, 1);
            nbr[idx] = (unsigned short)m;
        }
    }
    __syncthreads();
    int C = cnt_s;

    for (int h = 0; h < HH; h++) {
        const float* Qh = Q + ((size_t)(b * HH + h) * NN) * HDD;
        const float* Kh = K + ((size_t)(b * HH + h) * NN) * HDD;
        const float* Vh = V + ((size_t)(b * HH + h) * NN) * HDD;
        if (tid < HDD) q_sh[tid] = Qh[(size_t)n * HDD + tid];
        __syncthreads();

        // scores over neighbors
        float lmax = -1e30f;
        for (int i = tid; i < C; i += 256) {
            int m = nbr[i];
            const float* kp = Kh + (size_t)m * HDD;
            float s = 0.f;
#pragma unroll
            for (int d = 0; d < HDD; d++) s += q_sh[d] * kp[d];
            s *= inv_temp;
            sc[i] = s;
            lmax = fmaxf(lmax, s);
        }
        red[tid] = lmax;
        __syncthreads();
        for (int s2 = 128; s2 > 0; s2 >>= 1) {
            if (tid < s2) red[tid] = fmaxf(red[tid], red[tid + s2]);
            __syncthreads();
        }
        float rmax = red[0];
        __syncthreads();

        float lsum = 0.f;
        for (int i = tid; i < C; i += 256) {
            float p = __expf(sc[i] - rmax);
            sc[i] = p;
            lsum += p;
        }
        red[tid] = lsum;
        __syncthreads();
        for (int s2 = 128; s2 > 0; s2 >>= 1) {
            if (tid < s2) red[tid] += red[tid + s2];
            __syncthreads();
        }
        float inv_sum = 1.0f / red[0];
        __syncthreads();

        // attended = sum_m p[m] * V[m, :]
        int d = tid & (HDD - 1);
        int part = tid >> 5;   // 0..7
        float acc = 0.f;
        for (int i = part; i < C; i += 8) {
            acc += sc[i] * Vh[(size_t)nbr[i] * HDD + d];
        }
        part_s[part][d] = acc;

        // head-mean accumulation (each i owned by one thread; nbr unique)
        float wmean = inv_sum * (1.0f / HH);
        for (int i = tid; i < C; i += 256) meanrow[nbr[i]] += sc[i] * wmean;
        __syncthreads();

        if (tid < HDD) {
            float s = 0.f;
#pragma unroll
            for (int p = 0; p < 8; p++) s += part_s[p][tid];
            att[((size_t)(b * NN + n)) * DD + h * HDD + tid] = s * inv_sum;
        }
        __syncthreads();
    }

    size_t obase = (size_t)BB * NN * DD + (size_t)(b * NN + n) * NN;
    for (int m = tid; m < NN; m += 256) {
        stf(out, obase + m, meanrow[m], isbf);
    }
}

extern "C" void kernel_launch(void* const* d_in, const int* in_sizes, int n_in,
                              void* d_out, int out_size, void* d_ws, size_t ws_size,
                              hipStream_t stream) {
    const void* x  = d_in[0];
    const unsigned* ei = (const unsigned*)d_in[1];
    const void* Wq = d_in[2];
    const void* bq = d_in[3];
    const void* Wk = d_in[4];
    const void* bk = d_in[5];
    const void* Wv = d_in[6];
    const void* bv = d_in[7];
    const void* Wo = d_in[8];
    const void* bo = d_in[9];
    const unsigned short* tptr = (const unsigned short*)d_in[10];

    int E = in_sizes[1] / 2;

    char* ws = (char*)d_ws;
    unsigned* mask = (unsigned*)ws;                               // 512 KB
    float* Qw  = (float*)(ws + (size_t)NN * MASK_WORDS * 4);      // 8 MB each
    float* Kw  = Qw + (size_t)BB * NN * DD;
    float* Vw  = Kw + (size_t)BB * NN * DD;
    float* att = Vw + (size_t)BB * NN * DD;

    hipMemsetAsync(mask, 0, (size_t)NN * MASK_WORDS * 4, stream);

    int mth = (E > NN ? E : NN);
    build_mask_kernel<<<(mth + 255) / 256, 256, 0, stream>>>(ei, E, mask);

    dim3 pg(DD / 32, (BB * NN) / 32);
    proj_qkv_kernel<<<pg, 256, 0, stream>>>(x, Wq, bq, tptr, Qw);
    proj_qkv_kernel<<<pg, 256, 0, stream>>>(x, Wk, bk, tptr, Kw);
    proj_qkv_kernel<<<pg, 256, 0, stream>>>(x, Wv, bv, tptr, Vw);

    attn_kernel<<<BB * NN, 256, 0, stream>>>(Qw, Kw, Vw, mask, tptr, att, d_out);

    out_proj_kernel<<<pg, 256, 0, stream>>>(att, Wo, bo, tptr, d_out);
}